// Round 4
// baseline (223.179 us; speedup 1.0000x reference)
//
#include <hip/hip_runtime.h>
#include <hip/hip_bf16.h>
#include <math.h>

// TriangleAttention (starting node), N=256, c_z=128, H=4, C=32, fp32 in/out.
// Round 4: restore parallelism. Pipeline:
//   k_prep: weights -> bf16 rows [outcol][z] (Wq|Wk|Wv|Wg 0..511, Wo^T 512..639)
//   k_ln  : LayerNorm -> xb bf16 [p][128]; pair bias bT[h][k][q] fp32
//   k_head: grid (256 i, 4 h) x 256 thr (4 waves). Per block: K_h,V_h proj -> LDS,
//           Q_h,G_h per wave; attention + gate -> og bf16 [p][128] (head's cols)
//           ONE barrier per block; per-wave P staging in LDS (round-3-proven layouts)
//   k_out : out = og @ Wo^T + bo (round-2-proven GEMM)
// ws: xb @0 (16.8MB) | bT @16777216 (1MB) | Wt @17825792 (160KB) | og @17989632 (16.8MB)

#define NN 256
#define CZ 128

typedef __attribute__((ext_vector_type(8))) short bf16x8;
typedef __attribute__((ext_vector_type(4))) float f32x4;

__device__ __forceinline__ f32x4 mfma16(bf16x8 a, bf16x8 b, f32x4 c) {
  return __builtin_amdgcn_mfma_f32_16x16x32_bf16(a, b, c, 0, 0, 0);
}
__device__ __forceinline__ unsigned short f2bf(float f) {
  unsigned b = __float_as_uint(f);
  return (unsigned short)((b + 0x7FFFu + ((b >> 16) & 1u)) >> 16);
}

// ---------------- k_prep ----------------
__global__ __launch_bounds__(128) void k_prep(const float* __restrict__ Wq, const float* __restrict__ Wk,
                                              const float* __restrict__ Wv, const float* __restrict__ Wg,
                                              const float* __restrict__ Wo, unsigned short* __restrict__ Wt) {
  int n = blockIdx.x, t = threadIdx.x;
  const float* srcs[5] = {Wq, Wk, Wv, Wg, Wo};
  float v = srcs[n >> 7][t * 128 + (n & 127)];
  Wt[n * 128 + t] = f2bf(v);
}

// ---------------- k_ln ----------------
__global__ __launch_bounds__(256) void k_ln(const float* __restrict__ z,
                                            const float* __restrict__ ln_g,
                                            const float* __restrict__ ln_b,
                                            const float* __restrict__ Wb,
                                            unsigned short* __restrict__ xb,
                                            float* __restrict__ bT) {
  int wave = threadIdx.x >> 6, lane = threadIdx.x & 63;
  int pos = blockIdx.x * 4 + wave;
  float2 v = ((const float2*)(z + (size_t)pos * CZ))[lane];
  float s = v.x + v.y, sq = v.x * v.x + v.y * v.y;
#pragma unroll
  for (int o = 1; o < 64; o <<= 1) { s += __shfl_xor(s, o); sq += __shfl_xor(sq, o); }
  float mean = s * (1.0f / CZ);
  float var = sq * (1.0f / CZ) - mean * mean;
  float rstd = rsqrtf(var + 1e-5f);
  int c0 = lane * 2;
  float x0 = (v.x - mean) * rstd * ln_g[c0] + ln_b[c0];
  float x1 = (v.y - mean) * rstd * ln_g[c0 + 1] + ln_b[c0 + 1];
  unsigned pk = (unsigned)f2bf(x0) | ((unsigned)f2bf(x1) << 16);
  ((unsigned*)(xb + (size_t)pos * CZ))[lane] = pk;
  float4 w0 = *(const float4*)(Wb + c0 * 4);
  float4 w1 = *(const float4*)(Wb + (c0 + 1) * 4);
  float b0 = x0 * w0.x + x1 * w1.x;
  float b1 = x0 * w0.y + x1 * w1.y;
  float b2 = x0 * w0.z + x1 * w1.z;
  float b3 = x0 * w0.w + x1 * w1.w;
#pragma unroll
  for (int o = 1; o < 64; o <<= 1) {
    b0 += __shfl_xor(b0, o); b1 += __shfl_xor(b1, o);
    b2 += __shfl_xor(b2, o); b3 += __shfl_xor(b3, o);
  }
  if (lane == 0) {
    int j = pos >> 8, kk = pos & 255;
    bT[0 * 65536 + kk * 256 + j] = b0;   // bT[h][k][q]
    bT[1 * 65536 + kk * 256 + j] = b1;
    bT[2 * 65536 + kk * 256 + j] = b2;
    bT[3 * 65536 + kk * 256 + j] = b3;
  }
}

// ---------------- k_head: per-(i,h) proj + attention + gate ----------------
__global__ __launch_bounds__(256, 3) void k_head(const unsigned short* __restrict__ xb,
                                                 const unsigned short* __restrict__ Wt,
                                                 const float* __restrict__ bT,
                                                 const float* __restrict__ bg,
                                                 unsigned short* __restrict__ og) {
  __shared__ unsigned short ks[256][40];   // K_h [key][c]
  __shared__ unsigned short vt[32][264];   // V_h^T [c][key]
  __shared__ unsigned short qs[4][32][40]; // per-wave stage (Q, P, og)
  int i = blockIdx.x, h = blockIdx.y;
  int t = threadIdx.x, w = t >> 6, lane = t & 63, l16 = lane & 15, g = lane >> 4;
  const float sc = 0.17677669529663687f;  // 1/sqrt(32)

  bf16x8 qa[2][2];
  f32x4 gt[2][2][2];

  // ---- Phase A: projections for this wave's 64 rows (two 32-row halves) ----
#pragma unroll
  for (int rh = 0; rh < 2; rh++) {
    int r0 = w * 64 + rh * 32;  // absolute row (key idx == q idx range)
    bf16x8 xa[2][4];
#pragma unroll
    for (int m = 0; m < 2; m++)
#pragma unroll
      for (int kt = 0; kt < 4; kt++)
        xa[m][kt] = *(const bf16x8*)(xb + (size_t)(i * 256 + r0 + m * 16 + l16) * CZ + kt * 32 + g * 8);
    f32x4 d[2][2];
    // K_h
#pragma unroll
    for (int m = 0; m < 2; m++)
#pragma unroll
      for (int n = 0; n < 2; n++) d[m][n] = (f32x4){0.f, 0.f, 0.f, 0.f};
#pragma unroll
    for (int kt = 0; kt < 4; kt++)
#pragma unroll
      for (int n = 0; n < 2; n++) {
        bf16x8 b = *(const bf16x8*)(Wt + (size_t)(128 + h * 32 + n * 16 + l16) * CZ + kt * 32 + g * 8);
#pragma unroll
        for (int m = 0; m < 2; m++) d[m][n] = mfma16(xa[m][kt], b, d[m][n]);
      }
#pragma unroll
    for (int m = 0; m < 2; m++)
#pragma unroll
      for (int n = 0; n < 2; n++)
#pragma unroll
        for (int r = 0; r < 4; r++) ks[r0 + m * 16 + g * 4 + r][n * 16 + l16] = f2bf(d[m][n][r]);
    // V_h (transposed)
#pragma unroll
    for (int m = 0; m < 2; m++)
#pragma unroll
      for (int n = 0; n < 2; n++) d[m][n] = (f32x4){0.f, 0.f, 0.f, 0.f};
#pragma unroll
    for (int kt = 0; kt < 4; kt++)
#pragma unroll
      for (int n = 0; n < 2; n++) {
        bf16x8 b = *(const bf16x8*)(Wt + (size_t)(256 + h * 32 + n * 16 + l16) * CZ + kt * 32 + g * 8);
#pragma unroll
        for (int m = 0; m < 2; m++) d[m][n] = mfma16(xa[m][kt], b, d[m][n]);
      }
#pragma unroll
    for (int m = 0; m < 2; m++)
#pragma unroll
      for (int n = 0; n < 2; n++) {
        ushort4 pk;
        pk.x = f2bf(d[m][n][0]); pk.y = f2bf(d[m][n][1]);
        pk.z = f2bf(d[m][n][2]); pk.w = f2bf(d[m][n][3]);
        *(ushort4*)&vt[n * 16 + l16][r0 + m * 16 + g * 4] = pk;
      }
    // Q_h -> stage -> qa regs
#pragma unroll
    for (int m = 0; m < 2; m++)
#pragma unroll
      for (int n = 0; n < 2; n++) d[m][n] = (f32x4){0.f, 0.f, 0.f, 0.f};
#pragma unroll
    for (int kt = 0; kt < 4; kt++)
#pragma unroll
      for (int n = 0; n < 2; n++) {
        bf16x8 b = *(const bf16x8*)(Wt + (size_t)(0 + h * 32 + n * 16 + l16) * CZ + kt * 32 + g * 8);
#pragma unroll
        for (int m = 0; m < 2; m++) d[m][n] = mfma16(xa[m][kt], b, d[m][n]);
      }
#pragma unroll
    for (int m = 0; m < 2; m++)
#pragma unroll
      for (int n = 0; n < 2; n++)
#pragma unroll
        for (int r = 0; r < 4; r++) qs[w][m * 16 + g * 4 + r][n * 16 + l16] = f2bf(d[m][n][r]);
#pragma unroll
    for (int m = 0; m < 2; m++) qa[rh][m] = *(const bf16x8*)&qs[w][m * 16 + l16][g * 8];
    // G_h
#pragma unroll
    for (int m = 0; m < 2; m++)
#pragma unroll
      for (int n = 0; n < 2; n++) d[m][n] = (f32x4){0.f, 0.f, 0.f, 0.f};
#pragma unroll
    for (int kt = 0; kt < 4; kt++)
#pragma unroll
      for (int n = 0; n < 2; n++) {
        bf16x8 b = *(const bf16x8*)(Wt + (size_t)(384 + h * 32 + n * 16 + l16) * CZ + kt * 32 + g * 8);
#pragma unroll
        for (int m = 0; m < 2; m++) d[m][n] = mfma16(xa[m][kt], b, d[m][n]);
      }
    float bgv0 = bg[h * 32 + l16], bgv1 = bg[h * 32 + 16 + l16];
#pragma unroll
    for (int m = 0; m < 2; m++)
#pragma unroll
      for (int n = 0; n < 2; n++)
#pragma unroll
        for (int r = 0; r < 4; r++)
          gt[rh][m][n][r] = 1.0f / (1.0f + __expf(-(d[m][n][r] + (n ? bgv1 : bgv0))));
  }
  __syncthreads();  // ks, vt complete

  // ---- Phase B: attention, two 32-row q-halves ----
  const float* bb = bT + (size_t)h * 65536;
#pragma unroll
  for (int qh = 0; qh < 2; qh++) {
    int rq = w * 64 + qh * 32;
    f32x4 oat[2][2], lsum[2];
#pragma unroll
    for (int m = 0; m < 2; m++) {
      lsum[m] = (f32x4){0.f, 0.f, 0.f, 0.f};
#pragma unroll
      for (int n = 0; n < 2; n++) oat[m][n] = (f32x4){0.f, 0.f, 0.f, 0.f};
    }
    for (int kc = 0; kc < 8; kc++) {
      bf16x8 kb[2];
#pragma unroll
      for (int n = 0; n < 2; n++) kb[n] = *(const bf16x8*)&ks[kc * 32 + n * 16 + l16][g * 8];
      f32x4 p[2][2];
#pragma unroll
      for (int m = 0; m < 2; m++)
#pragma unroll
        for (int n = 0; n < 2; n++) {
          f32x4 s = mfma16(qa[qh][m], kb[n], (f32x4){0.f, 0.f, 0.f, 0.f});
          float4 bv = *(const float4*)(bb + (size_t)(kc * 32 + n * 16 + l16) * 256 + rq + m * 16 + g * 4);
          p[m][n][0] = __expf(s[0] * sc + bv.x);
          p[m][n][1] = __expf(s[1] * sc + bv.y);
          p[m][n][2] = __expf(s[2] * sc + bv.z);
          p[m][n][3] = __expf(s[3] * sc + bv.w);
          lsum[m] += p[m][n];
        }
#pragma unroll
      for (int m = 0; m < 2; m++)
#pragma unroll
        for (int n = 0; n < 2; n++)
#pragma unroll
          for (int r = 0; r < 4; r++) qs[w][m * 16 + g * 4 + r][n * 16 + l16] = f2bf(p[m][n][r]);
      bf16x8 pa[2], vb[2];
#pragma unroll
      for (int m = 0; m < 2; m++) pa[m] = *(const bf16x8*)&qs[w][m * 16 + l16][g * 8];
#pragma unroll
      for (int n = 0; n < 2; n++) vb[n] = *(const bf16x8*)&vt[n * 16 + l16][kc * 32 + g * 8];
#pragma unroll
      for (int m = 0; m < 2; m++)
#pragma unroll
        for (int n = 0; n < 2; n++) oat[m][n] = mfma16(pa[m], vb[n], oat[m][n]);
    }
#pragma unroll
    for (int m = 0; m < 2; m++)
#pragma unroll
      for (int off = 1; off < 16; off <<= 1)
#pragma unroll
        for (int r = 0; r < 4; r++) lsum[m][r] += __shfl_xor(lsum[m][r], off);
    // normalize + gate -> qs -> coalesced og store
#pragma unroll
    for (int m = 0; m < 2; m++) {
      f32x4 inv;
#pragma unroll
      for (int r = 0; r < 4; r++) inv[r] = 1.0f / lsum[m][r];
#pragma unroll
      for (int n = 0; n < 2; n++)
#pragma unroll
        for (int r = 0; r < 4; r++)
          qs[w][m * 16 + g * 4 + r][n * 16 + l16] = f2bf(oat[m][n][r] * inv[r] * gt[qh][m][n][r]);
    }
#pragma unroll
    for (int e = 0; e < 4; e++) {
      int idx = e * 64 + lane;
      int row = idx >> 3, c4 = (idx & 7) * 4;
      *(ushort4*)(og + (size_t)(i * 256 + rq + row) * 128 + h * 32 + c4) = *(ushort4*)&qs[w][row][c4];
    }
  }
}

// ---------------- k_out: MFMA output projection (round-2-proven) ----------------
__global__ __launch_bounds__(256) void k_out(const unsigned short* __restrict__ og,
                                             const unsigned short* __restrict__ WoT,
                                             const float* __restrict__ bo,
                                             float* __restrict__ out) {
  int t = threadIdx.x, w = t >> 6, lane = t & 63, l16 = lane & 15, g = lane >> 4;
  int wr = w >> 1, wc = w & 1;
  int pbase = blockIdx.x * 128 + wr * 64;
  int cbase = wc * 64;
  f32x4 acc[4][4];
#pragma unroll
  for (int m = 0; m < 4; m++)
#pragma unroll
    for (int n = 0; n < 4; n++) acc[m][n] = (f32x4){0.f, 0.f, 0.f, 0.f};
#pragma unroll
  for (int kt = 0; kt < 4; kt++) {
    bf16x8 a[4], b[4];
#pragma unroll
    for (int m = 0; m < 4; m++)
      a[m] = *(const bf16x8*)(og + (size_t)(pbase + m * 16 + l16) * 128 + kt * 32 + g * 8);
#pragma unroll
    for (int n = 0; n < 4; n++)
      b[n] = *(const bf16x8*)(WoT + (size_t)(cbase + n * 16 + l16) * 128 + kt * 32 + g * 8);
#pragma unroll
    for (int m = 0; m < 4; m++)
#pragma unroll
      for (int n = 0; n < 4; n++) acc[m][n] = mfma16(a[m], b[n], acc[m][n]);
  }
#pragma unroll
  for (int n = 0; n < 4; n++) {
    int zc = cbase + n * 16 + l16;
    float bv = bo[zc];
#pragma unroll
    for (int m = 0; m < 4; m++) {
#pragma unroll
      for (int r = 0; r < 4; r++)
        out[(size_t)(pbase + m * 16 + g * 4 + r) * 128 + zc] = acc[m][n][r] + bv;
    }
  }
}

extern "C" void kernel_launch(void* const* d_in, const int* in_sizes, int n_in,
                              void* d_out, int out_size, void* d_ws, size_t ws_size,
                              hipStream_t stream) {
  const float* z    = (const float*)d_in[0];
  const float* ln_g = (const float*)d_in[1];
  const float* ln_b = (const float*)d_in[2];
  const float* Wb   = (const float*)d_in[3];
  const float* Wq   = (const float*)d_in[4];
  const float* Wk   = (const float*)d_in[5];
  const float* Wv   = (const float*)d_in[6];
  const float* Wg   = (const float*)d_in[7];
  const float* bg   = (const float*)d_in[8];
  const float* Wo   = (const float*)d_in[9];
  const float* bo   = (const float*)d_in[10];
  float* out = (float*)d_out;

  char* ws = (char*)d_ws;
  unsigned short* xb = (unsigned short*)(ws + 0);
  float*          bT = (float*)(ws + 16777216);
  unsigned short* Wt = (unsigned short*)(ws + 17825792);
  unsigned short* og = (unsigned short*)(ws + 17989632);
  // total ws: 34,766,848 bytes

  k_prep<<<640, 128, 0, stream>>>(Wq, Wk, Wv, Wg, Wo, Wt);
  k_ln<<<16384, 256, 0, stream>>>(z, ln_g, ln_b, Wb, xb, bT);
  k_head<<<dim3(256, 4), 256, 0, stream>>>(xb, Wt, bT, bg, og);
  k_out<<<512, 256, 0, stream>>>(og, Wt + 512 * 128, bo, out);
}

// Round 5
// 213.908 us; speedup vs baseline: 1.0433x; 1.0433x over previous
//
#include <hip/hip_runtime.h>
#include <hip/hip_bf16.h>
#include <math.h>

// TriangleAttention (starting node), N=256, c_z=128, H=4, C=32, fp32 in/out.
// Round 5: latency attack. Swapped-QK in-register P (no LDS roundtrip),
// bias as MFMA C-operand (exp2 path), batched ILP loads, 37.4KB LDS -> 4 blocks/CU.
//   k_prep: weights -> bf16 rows [outcol][z] (Wq|Wk|Wv|Wg 0..511, Wo^T 512..639)
//   k_ln  : LayerNorm -> xb bf16 [p][128]; bias bN[h][q][k] fp32, pre-scaled log2e
//   k_head: grid (256 i, 4 h) x 256 thr (4 waves)
//   k_out : out = og @ Wo^T + bo
// ws: xb @0 (16.8MB) | bN @16777216 (1MB) | Wt @17825792 (160KB) | og @17989632 (16.8MB)

#define NN 256
#define CZ 128

typedef __attribute__((ext_vector_type(8))) short bf16x8;
typedef __attribute__((ext_vector_type(4))) float f32x4;

__device__ __forceinline__ f32x4 mfma16(bf16x8 a, bf16x8 b, f32x4 c) {
  return __builtin_amdgcn_mfma_f32_16x16x32_bf16(a, b, c, 0, 0, 0);
}
__device__ __forceinline__ unsigned short f2bf(float f) {
  unsigned b = __float_as_uint(f);
  return (unsigned short)((b + 0x7FFFu + ((b >> 16) & 1u)) >> 16);
}
__device__ __forceinline__ float bf2f(unsigned short u) { return __uint_as_float((unsigned)u << 16); }
__device__ __forceinline__ unsigned packbf(float a, float b) {
  return (unsigned)f2bf(a) | ((unsigned)f2bf(b) << 16);
}
// D-layout (lane: l16,g holds 4 vals at sub-idx g*4+r) -> A/B-frag (lane needs 8
// contiguous sub-idx g*8..g*8+7). pk[n][d]: d-th bf16-pair of the 4 vals of block n.
// target lane (l16,g): srcA = l16 + 32*(g&1), srcB = srcA+16, block n = g>>1.
__device__ __forceinline__ bf16x8 remap_frag(unsigned pk00, unsigned pk01,
                                             unsigned pk10, unsigned pk11,
                                             int srcA, int srcB, bool hi) {
  unsigned a0 = (unsigned)__shfl((int)pk00, srcA);
  unsigned b0 = (unsigned)__shfl((int)pk10, srcA);
  unsigned a1 = (unsigned)__shfl((int)pk01, srcA);
  unsigned b1 = (unsigned)__shfl((int)pk11, srcA);
  unsigned a2 = (unsigned)__shfl((int)pk00, srcB);
  unsigned b2 = (unsigned)__shfl((int)pk10, srcB);
  unsigned a3 = (unsigned)__shfl((int)pk01, srcB);
  unsigned b3 = (unsigned)__shfl((int)pk11, srcB);
  uint4 u;
  u.x = hi ? b0 : a0;
  u.y = hi ? b1 : a1;
  u.z = hi ? b2 : a2;
  u.w = hi ? b3 : a3;
  return *(bf16x8*)&u;
}

// ---------------- k_prep ----------------
__global__ __launch_bounds__(128) void k_prep(const float* __restrict__ Wq, const float* __restrict__ Wk,
                                              const float* __restrict__ Wv, const float* __restrict__ Wg,
                                              const float* __restrict__ Wo, unsigned short* __restrict__ Wt) {
  int sec = blockIdx.y, n = blockIdx.x, t = threadIdx.x;
  const float* s = sec == 0 ? Wq : sec == 1 ? Wk : sec == 2 ? Wv : sec == 3 ? Wg : Wo;
  Wt[(sec * 128 + n) * 128 + t] = f2bf(s[t * 128 + n]);
}

// ---------------- k_ln: LayerNorm + pair bias (natural layout, xlog2e) ----------------
__global__ __launch_bounds__(256) void k_ln(const float* __restrict__ z,
                                            const float* __restrict__ ln_g,
                                            const float* __restrict__ ln_b,
                                            const float* __restrict__ Wb,
                                            unsigned short* __restrict__ xb,
                                            float* __restrict__ bN) {
  int wave = threadIdx.x >> 6, lane = threadIdx.x & 63;
  int pos = blockIdx.x * 4 + wave;  // j = pos>>8 (q idx), k = pos&255 (key idx)
  float2 v = ((const float2*)(z + (size_t)pos * CZ))[lane];
  float s = v.x + v.y, sq = v.x * v.x + v.y * v.y;
#pragma unroll
  for (int o = 1; o < 64; o <<= 1) { s += __shfl_xor(s, o); sq += __shfl_xor(sq, o); }
  float mean = s * (1.0f / CZ);
  float var = sq * (1.0f / CZ) - mean * mean;
  float rstd = rsqrtf(var + 1e-5f);
  int c0 = lane * 2;
  float x0 = (v.x - mean) * rstd * ln_g[c0] + ln_b[c0];
  float x1 = (v.y - mean) * rstd * ln_g[c0 + 1] + ln_b[c0 + 1];
  unsigned pk = (unsigned)f2bf(x0) | ((unsigned)f2bf(x1) << 16);
  ((unsigned*)(xb + (size_t)pos * CZ))[lane] = pk;
  float4 w0 = *(const float4*)(Wb + c0 * 4);
  float4 w1 = *(const float4*)(Wb + (c0 + 1) * 4);
  float b0 = x0 * w0.x + x1 * w1.x;
  float b1 = x0 * w0.y + x1 * w1.y;
  float b2 = x0 * w0.z + x1 * w1.z;
  float b3 = x0 * w0.w + x1 * w1.w;
#pragma unroll
  for (int o = 1; o < 64; o <<= 1) {
    b0 += __shfl_xor(b0, o); b1 += __shfl_xor(b1, o);
    b2 += __shfl_xor(b2, o); b3 += __shfl_xor(b3, o);
  }
  if (lane == 0) {
    const float L2E = 1.4426950408889634f;
    int j = pos >> 8, kk = pos & 255;
    bN[0 * 65536 + j * 256 + kk] = b0 * L2E;  // bN[h][q][k], pre-scaled by log2(e)
    bN[1 * 65536 + j * 256 + kk] = b1 * L2E;
    bN[2 * 65536 + j * 256 + kk] = b2 * L2E;
    bN[3 * 65536 + j * 256 + kk] = b3 * L2E;
  }
}

// ---------------- k_head: per-(i,h) proj + attention + gate ----------------
__global__ __launch_bounds__(256, 4) void k_head(const unsigned short* __restrict__ xb,
                                                 const unsigned short* __restrict__ Wt,
                                                 const float* __restrict__ bN,
                                                 const float* __restrict__ bg,
                                                 unsigned short* __restrict__ og) {
  __shared__ unsigned short ks[256][40];   // K_h [key][c]
  __shared__ unsigned short vt[32][264];   // V_h^T [c][key]
  int i = blockIdx.x, h = blockIdx.y;
  int t = threadIdx.x, w = t >> 6, lane = t & 63, l16 = lane & 15, g = lane >> 4;
  const int srcA = l16 + 32 * (g & 1);
  const int srcB = srcA + 16;
  const bool hi = g >= 2;
  const float sc2 = 0.25503486f;  // log2(e)/sqrt(32)

  bf16x8 qa[4];          // QK B-frags: lane l16 -> q-row qB*16+l16, channels g*8..+7 (xsc2)
  unsigned gtp[4][2][2]; // sigmoid(G)^T packed: [qB][c-half][pair], c = n*16+g*4+r

  // ---- Phase A: per-wave 64 rows, two 32-row halves ----
#pragma unroll
  for (int rh = 0; rh < 2; rh++) {
    int r0 = w * 64 + rh * 32;  // block-local row base (q and key ranges coincide)
    // batched x A/B-frags (8 independent loads)
    bf16x8 xa[2][4];
#pragma unroll
    for (int m = 0; m < 2; m++)
#pragma unroll
      for (int kt = 0; kt < 4; kt++)
        xa[m][kt] = *(const bf16x8*)(xb + (size_t)(i * 256 + r0 + m * 16 + l16) * CZ + kt * 32 + g * 8);

    // ---- K (swapped: A=Wk cols, B=x rows) -> lane holds 4 consecutive c at fixed key
    {
      bf16x8 wf[2][4];
#pragma unroll
      for (int n = 0; n < 2; n++)
#pragma unroll
        for (int kt = 0; kt < 4; kt++)
          wf[n][kt] = *(const bf16x8*)(Wt + (size_t)(128 + h * 32 + n * 16 + l16) * CZ + kt * 32 + g * 8);
      f32x4 d[2][2];
#pragma unroll
      for (int m = 0; m < 2; m++)
#pragma unroll
        for (int n = 0; n < 2; n++) d[m][n] = (f32x4){0.f, 0.f, 0.f, 0.f};
#pragma unroll
      for (int kt = 0; kt < 4; kt++)
#pragma unroll
        for (int m = 0; m < 2; m++)
#pragma unroll
          for (int n = 0; n < 2; n++) d[m][n] = mfma16(wf[n][kt], xa[m][kt], d[m][n]);
#pragma unroll
      for (int m = 0; m < 2; m++)
#pragma unroll
        for (int n = 0; n < 2; n++) {
          ushort4 pk4;
          pk4.x = f2bf(d[m][n][0]); pk4.y = f2bf(d[m][n][1]);
          pk4.z = f2bf(d[m][n][2]); pk4.w = f2bf(d[m][n][3]);
          *(ushort4*)&ks[r0 + m * 16 + l16][n * 16 + g * 4] = pk4;
        }
    }
    // ---- V (normal: A=x rows, B=Wv cols) -> lane holds 4 consecutive keys at fixed c
    {
      bf16x8 wf[2][4];
#pragma unroll
      for (int n = 0; n < 2; n++)
#pragma unroll
        for (int kt = 0; kt < 4; kt++)
          wf[n][kt] = *(const bf16x8*)(Wt + (size_t)(256 + h * 32 + n * 16 + l16) * CZ + kt * 32 + g * 8);
      f32x4 d[2][2];
#pragma unroll
      for (int m = 0; m < 2; m++)
#pragma unroll
        for (int n = 0; n < 2; n++) d[m][n] = (f32x4){0.f, 0.f, 0.f, 0.f};
#pragma unroll
      for (int kt = 0; kt < 4; kt++)
#pragma unroll
        for (int m = 0; m < 2; m++)
#pragma unroll
          for (int n = 0; n < 2; n++) d[m][n] = mfma16(xa[m][kt], wf[n][kt], d[m][n]);
#pragma unroll
      for (int m = 0; m < 2; m++)
#pragma unroll
        for (int n = 0; n < 2; n++) {
          ushort4 pk4;
          pk4.x = f2bf(d[m][n][0]); pk4.y = f2bf(d[m][n][1]);
          pk4.z = f2bf(d[m][n][2]); pk4.w = f2bf(d[m][n][3]);
          *(ushort4*)&vt[n * 16 + l16][r0 + m * 16 + g * 4] = pk4;
        }
    }
    // ---- Q (swapped) -> scale by sc2, pack, remap to B-frag
    {
      bf16x8 wf[2][4];
#pragma unroll
      for (int n = 0; n < 2; n++)
#pragma unroll
        for (int kt = 0; kt < 4; kt++)
          wf[n][kt] = *(const bf16x8*)(Wt + (size_t)(0 + h * 32 + n * 16 + l16) * CZ + kt * 32 + g * 8);
      f32x4 d[2][2];
#pragma unroll
      for (int m = 0; m < 2; m++)
#pragma unroll
        for (int n = 0; n < 2; n++) d[m][n] = (f32x4){0.f, 0.f, 0.f, 0.f};
#pragma unroll
      for (int kt = 0; kt < 4; kt++)
#pragma unroll
        for (int m = 0; m < 2; m++)
#pragma unroll
          for (int n = 0; n < 2; n++) d[m][n] = mfma16(wf[n][kt], xa[m][kt], d[m][n]);
#pragma unroll
      for (int m = 0; m < 2; m++) {
        unsigned pk00 = packbf(d[m][0][0] * sc2, d[m][0][1] * sc2);
        unsigned pk01 = packbf(d[m][0][2] * sc2, d[m][0][3] * sc2);
        unsigned pk10 = packbf(d[m][1][0] * sc2, d[m][1][1] * sc2);
        unsigned pk11 = packbf(d[m][1][2] * sc2, d[m][1][3] * sc2);
        qa[rh * 2 + m] = remap_frag(pk00, pk01, pk10, pk11, srcA, srcB, hi);
      }
    }
    // ---- G (swapped; direct match to PV-output layout)
    {
      bf16x8 wf[2][4];
#pragma unroll
      for (int n = 0; n < 2; n++)
#pragma unroll
        for (int kt = 0; kt < 4; kt++)
          wf[n][kt] = *(const bf16x8*)(Wt + (size_t)(384 + h * 32 + n * 16 + l16) * CZ + kt * 32 + g * 8);
      f32x4 d[2][2];
#pragma unroll
      for (int m = 0; m < 2; m++)
#pragma unroll
        for (int n = 0; n < 2; n++) d[m][n] = (f32x4){0.f, 0.f, 0.f, 0.f};
#pragma unroll
      for (int kt = 0; kt < 4; kt++)
#pragma unroll
        for (int m = 0; m < 2; m++)
#pragma unroll
          for (int n = 0; n < 2; n++) d[m][n] = mfma16(wf[n][kt], xa[m][kt], d[m][n]);
#pragma unroll
      for (int n = 0; n < 2; n++) {
        float4 bgv = *(const float4*)(bg + h * 32 + n * 16 + g * 4);
#pragma unroll
        for (int m = 0; m < 2; m++) {
          float s0 = 1.0f / (1.0f + __expf(-(d[m][n][0] + bgv.x)));
          float s1 = 1.0f / (1.0f + __expf(-(d[m][n][1] + bgv.y)));
          float s2 = 1.0f / (1.0f + __expf(-(d[m][n][2] + bgv.z)));
          float s3 = 1.0f / (1.0f + __expf(-(d[m][n][3] + bgv.w)));
          gtp[rh * 2 + m][n][0] = packbf(s0, s1);
          gtp[rh * 2 + m][n][1] = packbf(s2, s3);
        }
      }
    }
  }
  __syncthreads();  // ks, vt complete

  // ---- Phase B: attention. O^T acc: lane (l16,g) -> q=qB*16+l16, c=n_c*16+g*4+r
  f32x4 oacc[4][2];
  float lsum[4];
#pragma unroll
  for (int qB = 0; qB < 4; qB++) {
    lsum[qB] = 0.f;
    oacc[qB][0] = (f32x4){0.f, 0.f, 0.f, 0.f};
    oacc[qB][1] = (f32x4){0.f, 0.f, 0.f, 0.f};
  }
  const float* bb = bN + (size_t)h * 65536;
#pragma unroll 2
  for (int kc = 0; kc < 8; kc++) {
    bf16x8 kb[2], vb[2];
#pragma unroll
    for (int n = 0; n < 2; n++) kb[n] = *(const bf16x8*)&ks[kc * 32 + n * 16 + l16][g * 8];
#pragma unroll
    for (int n = 0; n < 2; n++) vb[n] = *(const bf16x8*)&vt[n * 16 + l16][kc * 32 + g * 8];
#pragma unroll
    for (int qB = 0; qB < 4; qB++) {
      int qrow = w * 64 + qB * 16 + l16;
      float4 c0 = *(const float4*)(bb + (size_t)qrow * 256 + kc * 32 + 0 * 16 + g * 4);
      float4 c1 = *(const float4*)(bb + (size_t)qrow * 256 + kc * 32 + 1 * 16 + g * 4);
      f32x4 s0 = mfma16(kb[0], qa[qB], (f32x4){c0.x, c0.y, c0.z, c0.w});
      f32x4 s1 = mfma16(kb[1], qa[qB], (f32x4){c1.x, c1.y, c1.z, c1.w});
      float p0 = exp2f(s0[0]), p1 = exp2f(s0[1]), p2 = exp2f(s0[2]), p3 = exp2f(s0[3]);
      float p4 = exp2f(s1[0]), p5 = exp2f(s1[1]), p6 = exp2f(s1[2]), p7 = exp2f(s1[3]);
      lsum[qB] += ((p0 + p1) + (p2 + p3)) + ((p4 + p5) + (p6 + p7));
      unsigned pk00 = packbf(p0, p1), pk01 = packbf(p2, p3);
      unsigned pk10 = packbf(p4, p5), pk11 = packbf(p6, p7);
      bf16x8 pf = remap_frag(pk00, pk01, pk10, pk11, srcA, srcB, hi);
      oacc[qB][0] = mfma16(vb[0], pf, oacc[qB][0]);
      oacc[qB][1] = mfma16(vb[1], pf, oacc[qB][1]);
    }
  }
  // ---- epilogue: denom reduce over g, normalize, gate, store
#pragma unroll
  for (int qB = 0; qB < 4; qB++) {
    float l = lsum[qB];
    l += __shfl_xor(l, 16);
    l += __shfl_xor(l, 32);
    float inv = 1.0f / l;
#pragma unroll
    for (int nc = 0; nc < 2; nc++) {
      float g0 = bf2f((unsigned short)(gtp[qB][nc][0] & 0xffffu));
      float g1 = bf2f((unsigned short)(gtp[qB][nc][0] >> 16));
      float g2 = bf2f((unsigned short)(gtp[qB][nc][1] & 0xffffu));
      float g3 = bf2f((unsigned short)(gtp[qB][nc][1] >> 16));
      ushort4 pk4;
      pk4.x = f2bf(oacc[qB][nc][0] * inv * g0);
      pk4.y = f2bf(oacc[qB][nc][1] * inv * g1);
      pk4.z = f2bf(oacc[qB][nc][2] * inv * g2);
      pk4.w = f2bf(oacc[qB][nc][3] * inv * g3);
      *(ushort4*)(og + (size_t)(i * 256 + w * 64 + qB * 16 + l16) * 128 + h * 32 + nc * 16 + g * 4) = pk4;
    }
  }
}

// ---------------- k_out: MFMA output projection ----------------
__global__ __launch_bounds__(256) void k_out(const unsigned short* __restrict__ og,
                                             const unsigned short* __restrict__ WoT,
                                             const float* __restrict__ bo,
                                             float* __restrict__ out) {
  int t = threadIdx.x, w = t >> 6, lane = t & 63, l16 = lane & 15, g = lane >> 4;
  int wr = w >> 1, wc = w & 1;
  int pbase = blockIdx.x * 128 + wr * 64;
  int cbase = wc * 64;
  f32x4 acc[4][4];
#pragma unroll
  for (int m = 0; m < 4; m++)
#pragma unroll
    for (int n = 0; n < 4; n++) acc[m][n] = (f32x4){0.f, 0.f, 0.f, 0.f};
#pragma unroll
  for (int kt = 0; kt < 4; kt++) {
    bf16x8 a[4], b[4];
#pragma unroll
    for (int m = 0; m < 4; m++)
      a[m] = *(const bf16x8*)(og + (size_t)(pbase + m * 16 + l16) * 128 + kt * 32 + g * 8);
#pragma unroll
    for (int n = 0; n < 4; n++)
      b[n] = *(const bf16x8*)(WoT + (size_t)(cbase + n * 16 + l16) * 128 + kt * 32 + g * 8);
#pragma unroll
    for (int m = 0; m < 4; m++)
#pragma unroll
      for (int n = 0; n < 4; n++) acc[m][n] = mfma16(a[m], b[n], acc[m][n]);
  }
#pragma unroll
  for (int n = 0; n < 4; n++) {
    int zc = cbase + n * 16 + l16;
    float bv = bo[zc];
#pragma unroll
    for (int m = 0; m < 4; m++) {
#pragma unroll
      for (int r = 0; r < 4; r++)
        out[(size_t)(pbase + m * 16 + g * 4 + r) * 128 + zc] = acc[m][n][r] + bv;
    }
  }
}

extern "C" void kernel_launch(void* const* d_in, const int* in_sizes, int n_in,
                              void* d_out, int out_size, void* d_ws, size_t ws_size,
                              hipStream_t stream) {
  const float* z    = (const float*)d_in[0];
  const float* ln_g = (const float*)d_in[1];
  const float* ln_b = (const float*)d_in[2];
  const float* Wb   = (const float*)d_in[3];
  const float* Wq   = (const float*)d_in[4];
  const float* Wk   = (const float*)d_in[5];
  const float* Wv   = (const float*)d_in[6];
  const float* Wg   = (const float*)d_in[7];
  const float* bg   = (const float*)d_in[8];
  const float* Wo   = (const float*)d_in[9];
  const float* bo   = (const float*)d_in[10];
  float* out = (float*)d_out;

  char* ws = (char*)d_ws;
  unsigned short* xb = (unsigned short*)(ws + 0);
  float*          bN = (float*)(ws + 16777216);
  unsigned short* Wt = (unsigned short*)(ws + 17825792);
  unsigned short* og = (unsigned short*)(ws + 17989632);
  // total ws: 34,766,848 bytes

  k_prep<<<dim3(128, 5), 128, 0, stream>>>(Wq, Wk, Wv, Wg, Wo, Wt);
  k_ln<<<16384, 256, 0, stream>>>(z, ln_g, ln_b, Wb, xb, bN);
  k_head<<<dim3(256, 4), 256, 0, stream>>>(xb, Wt, bN, bg, og);
  k_out<<<512, 256, 0, stream>>>(og, Wt + 512 * 128, bo, out);
}

// Round 6
// 206.530 us; speedup vs baseline: 1.0806x; 1.0357x over previous
//
#include <hip/hip_runtime.h>
#include <hip/hip_bf16.h>
#include <math.h>

// TriangleAttention (starting node), N=256, c_z=128, H=4, C=32, fp32 in/out.
// Round 6: register-budget + coalescing attack.
//   k_prep: weights -> bf16 rows [outcol][z] (Wq|Wk|Wv|Wg 0..511, Wo^T 512..639)
//   k_ln  : LayerNorm via 4-lane-group reduce -> xb bf16; bias bN[h][q][k] fp32 (xlog2e)
//   k_head: grid (256 i, 4 h) x 256 thr; launch_bounds(256,3) -> deep load batching;
//           og staged via LDS (reuses ks) for coalesced 64B-line stores
//   k_out : og tile staged to padded LDS; out = og @ Wo^T + bo
// ws: xb @0 (16.8MB) | bN @16777216 (1MB) | Wt @17825792 (160KB) | og @17989632 (16.8MB)

#define NN 256
#define CZ 128

typedef __attribute__((ext_vector_type(8))) short bf16x8;
typedef __attribute__((ext_vector_type(4))) float f32x4;

__device__ __forceinline__ f32x4 mfma16(bf16x8 a, bf16x8 b, f32x4 c) {
  return __builtin_amdgcn_mfma_f32_16x16x32_bf16(a, b, c, 0, 0, 0);
}
__device__ __forceinline__ unsigned short f2bf(float f) {
  unsigned b = __float_as_uint(f);
  return (unsigned short)((b + 0x7FFFu + ((b >> 16) & 1u)) >> 16);
}
__device__ __forceinline__ float bf2f(unsigned short u) { return __uint_as_float((unsigned)u << 16); }
__device__ __forceinline__ unsigned packbf(float a, float b) {
  return (unsigned)f2bf(a) | ((unsigned)f2bf(b) << 16);
}
// D-layout (lane l16,g holds 4 vals at sub-idx g*4+r) -> A/B-frag (lane needs 8
// contiguous sub-idx g*8..g*8+7). srcA = l16 + 32*(g&1), srcB = srcA+16, hi = g>=2.
__device__ __forceinline__ bf16x8 remap_frag(unsigned pk00, unsigned pk01,
                                             unsigned pk10, unsigned pk11,
                                             int srcA, int srcB, bool hi) {
  unsigned a0 = (unsigned)__shfl((int)pk00, srcA);
  unsigned b0 = (unsigned)__shfl((int)pk10, srcA);
  unsigned a1 = (unsigned)__shfl((int)pk01, srcA);
  unsigned b1 = (unsigned)__shfl((int)pk11, srcA);
  unsigned a2 = (unsigned)__shfl((int)pk00, srcB);
  unsigned b2 = (unsigned)__shfl((int)pk10, srcB);
  unsigned a3 = (unsigned)__shfl((int)pk01, srcB);
  unsigned b3 = (unsigned)__shfl((int)pk11, srcB);
  uint4 u;
  u.x = hi ? b0 : a0;
  u.y = hi ? b1 : a1;
  u.z = hi ? b2 : a2;
  u.w = hi ? b3 : a3;
  return *(bf16x8*)&u;
}

// ---------------- k_prep ----------------
__global__ __launch_bounds__(128) void k_prep(const float* __restrict__ Wq, const float* __restrict__ Wk,
                                              const float* __restrict__ Wv, const float* __restrict__ Wg,
                                              const float* __restrict__ Wo, unsigned short* __restrict__ Wt) {
  int sec = blockIdx.y, n = blockIdx.x, t = threadIdx.x;
  const float* s = sec == 0 ? Wq : sec == 1 ? Wk : sec == 2 ? Wv : sec == 3 ? Wg : Wo;
  Wt[(sec * 128 + n) * 128 + t] = f2bf(s[t * 128 + n]);
}

// ---------------- k_ln: 4-lane-group LayerNorm + pair bias ----------------
// 1024 blocks x 256 thr; wave handles 16 positions; lane -> (pos = l>>2, quarter = l&3).
__global__ __launch_bounds__(256) void k_ln(const float* __restrict__ z,
                                            const float* __restrict__ ln_g,
                                            const float* __restrict__ ln_b,
                                            const float* __restrict__ Wb,
                                            unsigned short* __restrict__ xb,
                                            float* __restrict__ bN) {
  int t = threadIdx.x, wave = t >> 6, lane = t & 63;
  int p = blockIdx.x * 64 + wave * 16 + (lane >> 2);  // position (j,k) flat
  int q4 = lane & 3;                                   // c in [q4*32, q4*32+32)
  const float* src = z + (size_t)p * CZ + q4 * 32;
  float x[32];
  float s = 0.f, sq = 0.f;
#pragma unroll
  for (int e = 0; e < 8; e++) {
    float4 v = *(const float4*)(src + e * 4);
    x[e * 4 + 0] = v.x; x[e * 4 + 1] = v.y; x[e * 4 + 2] = v.z; x[e * 4 + 3] = v.w;
    s += (v.x + v.y) + (v.z + v.w);
    sq += (v.x * v.x + v.y * v.y) + (v.z * v.z + v.w * v.w);
  }
  s += __shfl_xor(s, 1); sq += __shfl_xor(sq, 1);
  s += __shfl_xor(s, 2); sq += __shfl_xor(sq, 2);
  float mean = s * (1.0f / CZ);
  float var = sq * (1.0f / CZ) - mean * mean;
  float rstd = rsqrtf(var + 1e-5f);
  float b0 = 0.f, b1 = 0.f, b2 = 0.f, b3 = 0.f;
  unsigned pk[16];
#pragma unroll
  for (int e = 0; e < 8; e++) {
    float4 gv = *(const float4*)(ln_g + q4 * 32 + e * 4);
    float4 bv = *(const float4*)(ln_b + q4 * 32 + e * 4);
    float x0 = (x[e * 4 + 0] - mean) * rstd * gv.x + bv.x;
    float x1 = (x[e * 4 + 1] - mean) * rstd * gv.y + bv.y;
    float x2 = (x[e * 4 + 2] - mean) * rstd * gv.z + bv.z;
    float x3 = (x[e * 4 + 3] - mean) * rstd * gv.w + bv.w;
    pk[e * 2 + 0] = packbf(x0, x1);
    pk[e * 2 + 1] = packbf(x2, x3);
    int zr = (q4 * 32 + e * 4) * 4;
    float4 w0 = *(const float4*)(Wb + zr);
    float4 w1 = *(const float4*)(Wb + zr + 4);
    float4 w2 = *(const float4*)(Wb + zr + 8);
    float4 w3 = *(const float4*)(Wb + zr + 12);
    b0 += x0 * w0.x + x1 * w1.x + x2 * w2.x + x3 * w3.x;
    b1 += x0 * w0.y + x1 * w1.y + x2 * w2.y + x3 * w3.y;
    b2 += x0 * w0.z + x1 * w1.z + x2 * w2.z + x3 * w3.z;
    b3 += x0 * w0.w + x1 * w1.w + x2 * w2.w + x3 * w3.w;
  }
  unsigned* dst = (unsigned*)(xb + (size_t)p * CZ + q4 * 32);
#pragma unroll
  for (int u = 0; u < 4; u++) ((uint4*)dst)[u] = ((uint4*)pk)[u];
  b0 += __shfl_xor(b0, 1); b1 += __shfl_xor(b1, 1);
  b2 += __shfl_xor(b2, 1); b3 += __shfl_xor(b3, 1);
  b0 += __shfl_xor(b0, 2); b1 += __shfl_xor(b1, 2);
  b2 += __shfl_xor(b2, 2); b3 += __shfl_xor(b3, 2);
  if (q4 == 0) {
    const float L2E = 1.4426950408889634f;
    int j = p >> 8, kk = p & 255;
    bN[0 * 65536 + j * 256 + kk] = b0 * L2E;  // bN[h][q][k], pre-scaled by log2(e)
    bN[1 * 65536 + j * 256 + kk] = b1 * L2E;
    bN[2 * 65536 + j * 256 + kk] = b2 * L2E;
    bN[3 * 65536 + j * 256 + kk] = b3 * L2E;
  }
}

// ---------------- k_head: per-(i,h) proj + attention + gate ----------------
__global__ __launch_bounds__(256, 3) void k_head(const unsigned short* __restrict__ xb,
                                                 const unsigned short* __restrict__ Wt,
                                                 const float* __restrict__ bN,
                                                 const float* __restrict__ bg,
                                                 unsigned short* __restrict__ og) {
  __shared__ unsigned short ks[256][40];   // K_h [key][c]; reused as og stage at end
  __shared__ unsigned short vt[32][264];   // V_h^T [c][key]
  int i = blockIdx.x, h = blockIdx.y;
  int t = threadIdx.x, w = t >> 6, lane = t & 63, l16 = lane & 15, g = lane >> 4;
  const int srcA = l16 + 32 * (g & 1);
  const int srcB = srcA + 16;
  const bool hi = g >= 2;
  const float sc2 = 0.25503486f;  // log2(e)/sqrt(32)

  bf16x8 qa[4];          // QK B-frags
  unsigned gtp[4][2][2]; // sigmoid(G)^T packed

  // ---- all x A/B-frags for this wave's 64 rows, hoisted (16 loads) ----
  bf16x8 xa[4][4];
#pragma unroll
  for (int mm = 0; mm < 4; mm++)
#pragma unroll
    for (int kt = 0; kt < 4; kt++)
      xa[mm][kt] = *(const bf16x8*)(xb + (size_t)(i * 256 + w * 64 + mm * 16 + l16) * CZ + kt * 32 + g * 8);

  // ---- Phase A, section-major (wf loaded once per section) ----
  // K (swapped: lane -> 4 consecutive c at fixed key)
  {
    bf16x8 wf[2][4];
#pragma unroll
    for (int n = 0; n < 2; n++)
#pragma unroll
      for (int kt = 0; kt < 4; kt++)
        wf[n][kt] = *(const bf16x8*)(Wt + (size_t)(128 + h * 32 + n * 16 + l16) * CZ + kt * 32 + g * 8);
#pragma unroll
    for (int rh = 0; rh < 2; rh++) {
      f32x4 d[2][2];
#pragma unroll
      for (int m = 0; m < 2; m++)
#pragma unroll
        for (int n = 0; n < 2; n++) d[m][n] = (f32x4){0.f, 0.f, 0.f, 0.f};
#pragma unroll
      for (int kt = 0; kt < 4; kt++)
#pragma unroll
        for (int m = 0; m < 2; m++)
#pragma unroll
          for (int n = 0; n < 2; n++) d[m][n] = mfma16(wf[n][kt], xa[rh * 2 + m][kt], d[m][n]);
#pragma unroll
      for (int m = 0; m < 2; m++)
#pragma unroll
        for (int n = 0; n < 2; n++) {
          ushort4 pk4;
          pk4.x = f2bf(d[m][n][0]); pk4.y = f2bf(d[m][n][1]);
          pk4.z = f2bf(d[m][n][2]); pk4.w = f2bf(d[m][n][3]);
          *(ushort4*)&ks[w * 64 + rh * 32 + m * 16 + l16][n * 16 + g * 4] = pk4;
        }
    }
  }
  // V (normal: lane -> 4 consecutive keys at fixed c; store transposed)
  {
    bf16x8 wf[2][4];
#pragma unroll
    for (int n = 0; n < 2; n++)
#pragma unroll
      for (int kt = 0; kt < 4; kt++)
        wf[n][kt] = *(const bf16x8*)(Wt + (size_t)(256 + h * 32 + n * 16 + l16) * CZ + kt * 32 + g * 8);
#pragma unroll
    for (int rh = 0; rh < 2; rh++) {
      f32x4 d[2][2];
#pragma unroll
      for (int m = 0; m < 2; m++)
#pragma unroll
        for (int n = 0; n < 2; n++) d[m][n] = (f32x4){0.f, 0.f, 0.f, 0.f};
#pragma unroll
      for (int kt = 0; kt < 4; kt++)
#pragma unroll
        for (int m = 0; m < 2; m++)
#pragma unroll
          for (int n = 0; n < 2; n++) d[m][n] = mfma16(xa[rh * 2 + m][kt], wf[n][kt], d[m][n]);
#pragma unroll
      for (int m = 0; m < 2; m++)
#pragma unroll
        for (int n = 0; n < 2; n++) {
          ushort4 pk4;
          pk4.x = f2bf(d[m][n][0]); pk4.y = f2bf(d[m][n][1]);
          pk4.z = f2bf(d[m][n][2]); pk4.w = f2bf(d[m][n][3]);
          *(ushort4*)&vt[n * 16 + l16][w * 64 + rh * 32 + m * 16 + g * 4] = pk4;
        }
    }
  }
  // Q (swapped) -> scale, pack, remap to B-frag
  {
    bf16x8 wf[2][4];
#pragma unroll
    for (int n = 0; n < 2; n++)
#pragma unroll
      for (int kt = 0; kt < 4; kt++)
        wf[n][kt] = *(const bf16x8*)(Wt + (size_t)(0 + h * 32 + n * 16 + l16) * CZ + kt * 32 + g * 8);
#pragma unroll
    for (int rh = 0; rh < 2; rh++) {
      f32x4 d[2][2];
#pragma unroll
      for (int m = 0; m < 2; m++)
#pragma unroll
        for (int n = 0; n < 2; n++) d[m][n] = (f32x4){0.f, 0.f, 0.f, 0.f};
#pragma unroll
      for (int kt = 0; kt < 4; kt++)
#pragma unroll
        for (int m = 0; m < 2; m++)
#pragma unroll
          for (int n = 0; n < 2; n++) d[m][n] = mfma16(wf[n][kt], xa[rh * 2 + m][kt], d[m][n]);
#pragma unroll
      for (int m = 0; m < 2; m++) {
        unsigned pk00 = packbf(d[m][0][0] * sc2, d[m][0][1] * sc2);
        unsigned pk01 = packbf(d[m][0][2] * sc2, d[m][0][3] * sc2);
        unsigned pk10 = packbf(d[m][1][0] * sc2, d[m][1][1] * sc2);
        unsigned pk11 = packbf(d[m][1][2] * sc2, d[m][1][3] * sc2);
        qa[rh * 2 + m] = remap_frag(pk00, pk01, pk10, pk11, srcA, srcB, hi);
      }
    }
  }
  // G (swapped; direct match to PV-output layout)
  {
    bf16x8 wf[2][4];
#pragma unroll
    for (int n = 0; n < 2; n++)
#pragma unroll
      for (int kt = 0; kt < 4; kt++)
        wf[n][kt] = *(const bf16x8*)(Wt + (size_t)(384 + h * 32 + n * 16 + l16) * CZ + kt * 32 + g * 8);
#pragma unroll
    for (int rh = 0; rh < 2; rh++) {
      f32x4 d[2][2];
#pragma unroll
      for (int m = 0; m < 2; m++)
#pragma unroll
        for (int n = 0; n < 2; n++) d[m][n] = (f32x4){0.f, 0.f, 0.f, 0.f};
#pragma unroll
      for (int kt = 0; kt < 4; kt++)
#pragma unroll
        for (int m = 0; m < 2; m++)
#pragma unroll
          for (int n = 0; n < 2; n++) d[m][n] = mfma16(wf[n][kt], xa[rh * 2 + m][kt], d[m][n]);
#pragma unroll
      for (int n = 0; n < 2; n++) {
        float4 bgv = *(const float4*)(bg + h * 32 + n * 16 + g * 4);
#pragma unroll
        for (int m = 0; m < 2; m++) {
          float s0 = 1.0f / (1.0f + __expf(-(d[m][n][0] + bgv.x)));
          float s1 = 1.0f / (1.0f + __expf(-(d[m][n][1] + bgv.y)));
          float s2 = 1.0f / (1.0f + __expf(-(d[m][n][2] + bgv.z)));
          float s3 = 1.0f / (1.0f + __expf(-(d[m][n][3] + bgv.w)));
          gtp[rh * 2 + m][n][0] = packbf(s0, s1);
          gtp[rh * 2 + m][n][1] = packbf(s2, s3);
        }
      }
    }
  }
  __syncthreads();  // ks, vt complete

  // ---- Phase B: attention with next-kc LDS prefetch ----
  f32x4 oacc[4][2];
  float lsum[4];
#pragma unroll
  for (int qB = 0; qB < 4; qB++) {
    lsum[qB] = 0.f;
    oacc[qB][0] = (f32x4){0.f, 0.f, 0.f, 0.f};
    oacc[qB][1] = (f32x4){0.f, 0.f, 0.f, 0.f};
  }
  const float* bb = bN + (size_t)h * 65536;
  bf16x8 kb[2], vb[2], kbn[2], vbn[2];
#pragma unroll
  for (int n = 0; n < 2; n++) {
    kb[n] = *(const bf16x8*)&ks[0 * 32 + n * 16 + l16][g * 8];
    vb[n] = *(const bf16x8*)&vt[n * 16 + l16][0 * 32 + g * 8];
  }
#pragma unroll 2
  for (int kc = 0; kc < 8; kc++) {
    if (kc < 7) {
#pragma unroll
      for (int n = 0; n < 2; n++) {
        kbn[n] = *(const bf16x8*)&ks[(kc + 1) * 32 + n * 16 + l16][g * 8];
        vbn[n] = *(const bf16x8*)&vt[n * 16 + l16][(kc + 1) * 32 + g * 8];
      }
    }
#pragma unroll
    for (int qB = 0; qB < 4; qB++) {
      int qrow = w * 64 + qB * 16 + l16;
      float4 c0 = *(const float4*)(bb + (size_t)qrow * 256 + kc * 32 + 0 * 16 + g * 4);
      float4 c1 = *(const float4*)(bb + (size_t)qrow * 256 + kc * 32 + 1 * 16 + g * 4);
      f32x4 s0 = mfma16(kb[0], qa[qB], (f32x4){c0.x, c0.y, c0.z, c0.w});
      f32x4 s1 = mfma16(kb[1], qa[qB], (f32x4){c1.x, c1.y, c1.z, c1.w});
      float p0 = exp2f(s0[0]), p1 = exp2f(s0[1]), p2 = exp2f(s0[2]), p3 = exp2f(s0[3]);
      float p4 = exp2f(s1[0]), p5 = exp2f(s1[1]), p6 = exp2f(s1[2]), p7 = exp2f(s1[3]);
      lsum[qB] += ((p0 + p1) + (p2 + p3)) + ((p4 + p5) + (p6 + p7));
      unsigned pk00 = packbf(p0, p1), pk01 = packbf(p2, p3);
      unsigned pk10 = packbf(p4, p5), pk11 = packbf(p6, p7);
      bf16x8 pf = remap_frag(pk00, pk01, pk10, pk11, srcA, srcB, hi);
      oacc[qB][0] = mfma16(vb[0], pf, oacc[qB][0]);
      oacc[qB][1] = mfma16(vb[1], pf, oacc[qB][1]);
    }
    kb[0] = kbn[0]; kb[1] = kbn[1]; vb[0] = vbn[0]; vb[1] = vbn[1];
  }
  // ---- epilogue: stage gated/normalized O into ks region, coalesced og write ----
  __syncthreads();  // everyone done reading ks/vt
  unsigned short* myst = &ks[w * 64][0];  // per-wave [64][40] view
#pragma unroll
  for (int qB = 0; qB < 4; qB++) {
    float l = lsum[qB];
    l += __shfl_xor(l, 16);
    l += __shfl_xor(l, 32);
    float inv = 1.0f / l;
#pragma unroll
    for (int nc = 0; nc < 2; nc++) {
      float g0 = bf2f((unsigned short)(gtp[qB][nc][0] & 0xffffu));
      float g1 = bf2f((unsigned short)(gtp[qB][nc][0] >> 16));
      float g2 = bf2f((unsigned short)(gtp[qB][nc][1] & 0xffffu));
      float g3 = bf2f((unsigned short)(gtp[qB][nc][1] >> 16));
      ushort4 pk4;
      pk4.x = f2bf(oacc[qB][nc][0] * inv * g0);
      pk4.y = f2bf(oacc[qB][nc][1] * inv * g1);
      pk4.z = f2bf(oacc[qB][nc][2] * inv * g2);
      pk4.w = f2bf(oacc[qB][nc][3] * inv * g3);
      *(ushort4*)&myst[(qB * 16 + l16) * 40 + nc * 16 + g * 4] = pk4;
    }
  }
#pragma unroll
  for (int e = 0; e < 8; e++) {
    int row = e * 8 + (lane >> 3), chunk = lane & 7;
    *(ushort4*)(og + (size_t)(i * 256 + w * 64 + row) * 128 + h * 32 + chunk * 4) =
        *(const ushort4*)&myst[row * 40 + chunk * 4];
  }
}

// ---------------- k_out: LDS-staged MFMA output projection ----------------
__global__ __launch_bounds__(256, 4) void k_out(const unsigned short* __restrict__ og,
                                                const unsigned short* __restrict__ WoT,
                                                const float* __restrict__ bo,
                                                float* __restrict__ out) {
  __shared__ unsigned short ot[128][136];  // og tile, +8 pad -> 2-way banks
  int t = threadIdx.x, w = t >> 6, lane = t & 63, l16 = lane & 15, g = lane >> 4;
  int wr = w >> 1, wc = w & 1;
  int pbase = blockIdx.x * 128;
  // stage og tile (coalesced 16B loads, padded LDS writes)
#pragma unroll
  for (int e = 0; e < 8; e++) {
    int idx = e * 256 + t;          // 16B chunk id; 16 chunks per row
    int row = idx >> 4, chunk = idx & 15;
    uint4 v = *(const uint4*)(og + (size_t)(pbase + row) * 128 + chunk * 8);
    *(uint4*)&ot[row][chunk * 8] = v;
  }
  __syncthreads();
  int prow = wr * 64, cbase = wc * 64;
  f32x4 acc[4][4];
#pragma unroll
  for (int m = 0; m < 4; m++)
#pragma unroll
    for (int n = 0; n < 4; n++) acc[m][n] = (f32x4){0.f, 0.f, 0.f, 0.f};
#pragma unroll
  for (int kt = 0; kt < 4; kt++) {
    bf16x8 a[4], b[4];
#pragma unroll
    for (int m = 0; m < 4; m++)
      a[m] = *(const bf16x8*)&ot[prow + m * 16 + l16][kt * 32 + g * 8];
#pragma unroll
    for (int n = 0; n < 4; n++)
      b[n] = *(const bf16x8*)(WoT + (size_t)(cbase + n * 16 + l16) * 128 + kt * 32 + g * 8);
#pragma unroll
    for (int m = 0; m < 4; m++)
#pragma unroll
      for (int n = 0; n < 4; n++) acc[m][n] = mfma16(a[m], b[n], acc[m][n]);
  }
#pragma unroll
  for (int n = 0; n < 4; n++) {
    int zc = cbase + n * 16 + l16;
    float bv = bo[zc];
#pragma unroll
    for (int m = 0; m < 4; m++) {
#pragma unroll
      for (int r = 0; r < 4; r++)
        out[(size_t)(pbase + prow + m * 16 + g * 4 + r) * 128 + zc] = acc[m][n][r] + bv;
    }
  }
}

extern "C" void kernel_launch(void* const* d_in, const int* in_sizes, int n_in,
                              void* d_out, int out_size, void* d_ws, size_t ws_size,
                              hipStream_t stream) {
  const float* z    = (const float*)d_in[0];
  const float* ln_g = (const float*)d_in[1];
  const float* ln_b = (const float*)d_in[2];
  const float* Wb   = (const float*)d_in[3];
  const float* Wq   = (const float*)d_in[4];
  const float* Wk   = (const float*)d_in[5];
  const float* Wv   = (const float*)d_in[6];
  const float* Wg   = (const float*)d_in[7];
  const float* bg   = (const float*)d_in[8];
  const float* Wo   = (const float*)d_in[9];
  const float* bo   = (const float*)d_in[10];
  float* out = (float*)d_out;

  char* ws = (char*)d_ws;
  unsigned short* xb = (unsigned short*)(ws + 0);
  float*          bN = (float*)(ws + 16777216);
  unsigned short* Wt = (unsigned short*)(ws + 17825792);
  unsigned short* og = (unsigned short*)(ws + 17989632);
  // total ws: 34,766,848 bytes

  k_prep<<<dim3(128, 5), 128, 0, stream>>>(Wq, Wk, Wv, Wg, Wo, Wt);
  k_ln<<<1024, 256, 0, stream>>>(z, ln_g, ln_b, Wb, xb, bN);
  k_head<<<dim3(256, 4), 256, 0, stream>>>(xb, Wt, bN, bg, og);
  k_out<<<512, 256, 0, stream>>>(og, Wt + 512 * 128, bo, out);
}